// Round 1
// 299.050 us; speedup vs baseline: 1.0020x; 1.0020x over previous
//
#include <hip/hip_runtime.h>
#include <stdint.h>

// Problem constants: B=8, N=2048, F_in=F_out=512
#define NB 8
#define NN 2048
#define NF 512
#define TOTN (NB * NN)   // 16384 nodes total

typedef unsigned short u16;
typedef short bf16x8 __attribute__((ext_vector_type(8)));
typedef float f32x4 __attribute__((ext_vector_type(4)));

__device__ __forceinline__ u16 f2bf(float x) {
  unsigned u = __float_as_uint(x);
  unsigned r = 0x7FFFu + ((u >> 16) & 1u);
  return (u16)((u + r) >> 16);
}

__device__ __forceinline__ void gl2lds16(const void* g, void* l) {
  // async global->LDS, 16B per lane; LDS dst = wave-uniform base + lane*16
  __builtin_amdgcn_global_load_lds((const __attribute__((address_space(1))) void*)g,
                                   (__attribute__((address_space(3))) void*)l,
                                   16, 0, 0);
}

// slab swizzle: within a 16-row chunk, data (row rc, k-quarter q) lives at
// slot = rc*4 + (q ^ ((rc>>1)&3)), 16 B per slot.  (verified conflict-free R3)

// ---------------------------------------------------------------------------
// K1 (merged prep): text fp32->bf16, W->W^T bf16, adj->bitmask, zero s/d.
// One dispatch instead of three (conv + pack + memset): fewer launch gaps.
// ---------------------------------------------------------------------------
__global__ __launch_bounds__(256) void prep_kernel(
    const float* __restrict__ text, const float* __restrict__ W,
    const int* __restrict__ adj, u16* __restrict__ text_bf,
    u16* __restrict__ Wt, uint32_t* __restrict__ bm,
    float* __restrict__ sd) {
  int blk = blockIdx.x;
  if (blk < 8192) {
    // text conversion: 8192 blocks x 256 thr x float4
    int idx = blk * 256 + threadIdx.x;
    float4 v = ((const float4*)text)[idx];
    ushort4 o;
    o.x = f2bf(v.x); o.y = f2bf(v.y); o.z = f2bf(v.z); o.w = f2bf(v.w);
    ((ushort4*)text_bf)[idx] = o;
  } else if (blk < 9216) {
    // W transpose+convert: 1024 blocks
    int t = (blk - 8192) * 256 + threadIdx.x;
    int o = t >> 9, f = t & 511;
    Wt[o * NF + f] = f2bf(W[f * NF + o]);
  } else if (blk < 13312) {
    // adj pack (int32 0/1 -> bitmask), 32 elems/thread: 4096 blocks
    int gid = (blk - 9216) * 256 + threadIdx.x;
    const int4* p = (const int4*)(adj + (size_t)gid * 32);
    uint32_t bits = 0;
#pragma unroll
    for (int c = 0; c < 8; ++c) {
      int4 a = p[c];
      bits |= (uint32_t)(a.x != 0) << (c * 4 + 0);
      bits |= (uint32_t)(a.y != 0) << (c * 4 + 1);
      bits |= (uint32_t)(a.z != 0) << (c * 4 + 2);
      bits |= (uint32_t)(a.w != 0) << (c * 4 + 3);
    }
    bm[gid] = bits;
  } else {
    // zero s,d (contiguous 131072 B = 8192 float4): 1 block
    float4* p = (float4*)sd;
#pragma unroll
    for (int c = 0; c < 32; ++c)
      p[c * 256 + threadIdx.x] = (float4){0.f, 0.f, 0.f, 0.f};
  }
}

// ---------------------------------------------------------------------------
// K3: GEMM1 hidden[o][node] -> pre-swizzled slabs + fused s/d score epilogue.
// hS layout: [z 8][oh 2][kc 64][16KB slab image]; image = 16 chunks(16 o-rows)
// x swizzled slots. Slab (z,oh,kc) holds hidden[o in oh*256..+256][k=kc*32..+32].
// ---------------------------------------------------------------------------
__global__ __launch_bounds__(256) void gemm1_kernel(
    const u16* __restrict__ A,   // Wt [512][512]
    const u16* __restrict__ Bt,  // text_bf [16384][512]
    const float* __restrict__ bias, const float* __restrict__ a_src,
    const float* __restrict__ a_dst, u16* __restrict__ hS,
    float* __restrict__ s, float* __restrict__ d) {
  __shared__ u16 Alds[128 * 32];
  __shared__ u16 Blds[128 * 32];

  const int bn = blockIdx.x, bm_ = blockIdx.y;
  const int t = threadIdx.x, wave = t >> 6, lane = t & 63;
  const int wm = (wave >> 1) * 64, wn = (wave & 1) * 64;

  f32x4 acc[4][4];
#pragma unroll
  for (int i = 0; i < 4; ++i)
#pragma unroll
    for (int j = 0; j < 4; ++j) acc[i][j] = (f32x4){0.f, 0.f, 0.f, 0.f};

  const int rowA0 = bm_ * 128, rowB0 = bn * 128;
  const int srow = (lane >> 2);
  const int scol = (lane & 3) * 8;

  for (int kt = 0; kt < NF; kt += 32) {
#pragma unroll
    for (int q = 0; q < 2; ++q) {
      int r = wave * 32 + q * 16;
      gl2lds16(A + (size_t)(rowA0 + r + srow) * NF + (kt + scol), &Alds[r * 32]);
    }
#pragma unroll
    for (int q = 0; q < 2; ++q) {
      int r = wave * 32 + q * 16;
      gl2lds16(Bt + (size_t)(rowB0 + r + srow) * NF + (kt + scol), &Blds[r * 32]);
    }
    __syncthreads();

    const int fr = lane & 15;
    const int k0 = (lane >> 4) * 8;
    bf16x8 af[4], bfr[4];
#pragma unroll
    for (int i = 0; i < 4; ++i)
      af[i] = *(const bf16x8*)&Alds[(wm + i * 16 + fr) * 32 + k0];
#pragma unroll
    for (int j = 0; j < 4; ++j)
      bfr[j] = *(const bf16x8*)&Blds[(wn + j * 16 + fr) * 32 + k0];
#pragma unroll
    for (int i = 0; i < 4; ++i)
#pragma unroll
      for (int j = 0; j < 4; ++j)
        acc[i][j] = __builtin_amdgcn_mfma_f32_16x16x32_bf16(af[i], bfr[j],
                                                            acc[i][j], 0, 0, 0);
    __syncthreads();
  }

  const int quad = lane >> 4, ln16 = lane & 15;
  float sa[4] = {0.f, 0.f, 0.f, 0.f}, da[4] = {0.f, 0.f, 0.f, 0.f};
#pragma unroll
  for (int i = 0; i < 4; ++i) {
    int m0 = bm_ * 128 + wm + i * 16 + quad * 4;
#pragma unroll
    for (int r = 0; r < 4; ++r) {
      int m = m0 + r;
      float bv = bias[m];
      float asv = a_src[m], adv = a_dst[m];
      int oh = m >> 8, och = (m >> 4) & 15, rc = m & 15;
#pragma unroll
      for (int j = 0; j < 4; ++j) {
        int n = bn * 128 + wn + j * 16 + ln16;
        float h = acc[i][j][r] + bv;
        int zz = n >> 11, nz = n & 2047;
        int kc = nz >> 5, kin = nz & 31;
        size_t off = ((((size_t)zz * 2 + oh) * 64 + kc) << 13)  // slab, u16 units
                     + (och << 9)
                     + ((size_t)(rc * 4 + ((kin >> 3) ^ ((rc >> 1) & 3))) << 3)
                     + (kin & 7);
        hS[off] = f2bf(h);
        sa[j] = fmaf(h, asv, sa[j]);
        da[j] = fmaf(h, adv, da[j]);
      }
    }
  }
#pragma unroll
  for (int j = 0; j < 4; ++j) {
    float v = sa[j] + __shfl_xor(sa[j], 16, 64);
    v += __shfl_xor(v, 32, 64);
    float w2 = da[j] + __shfl_xor(da[j], 16, 64);
    w2 += __shfl_xor(w2, 32, 64);
    if (quad == 0) {
      int n = bn * 128 + wn + j * 16 + ln16;
      atomicAdd(&s[n], v);
      atomicAdd(&d[n], w2);
    }
  }
}

// ---------------------------------------------------------------------------
// K4 (fused): out[z,i,o] = (1/l_i)*sum_j exp(lrelu(s_i+d_j))·[!adj]·h[j][o]
// 64(i) x 256(o) tile, 4 waves (each 64x64), BK=64, grid (32,2,8)=512 blocks.
//
// PIPELINED (T3+T4): double-buffered B slabs, raw s_barrier (no vmcnt(0)
// drain), counted waits. Per-iter per-wave vmem issue order:
//   [dv/bw prefetch x5][stage(kt+1) gl2lds x8]  -> at next iter's P-compute
// the compiler waits vmcnt(8) for dv (stage stays in flight); before MFMA we
// wait vmcnt(13) = drain only the PREVIOUS tile's 8 staging ops.
// Barriers: E (after vmcnt wait: B[cur] staged + P written by all waves),
//           G (after MFMA: all ds_reads of B[cur]/Plds complete before the
//              next iteration may overwrite them).
// LDS: 64K (2xB) + 8K (P) + 1.25K = 73.3 KB -> still 2 blocks/CU.
// ---------------------------------------------------------------------------
__global__ __launch_bounds__(256, 2) void fused_attn_kernel(
    const uint32_t* __restrict__ bm, const float* __restrict__ s,
    const float* __restrict__ d, const u16* __restrict__ hS,
    float* __restrict__ out) {
  __shared__ u16 Blds[2][16384];   // 2 x 32 KB double buffer
  __shared__ u16 Plds[4096];       // 8 KB = 2 k-half images
  __shared__ float lpart[256];
  __shared__ float linv_lds[64];

  const int z = blockIdx.z, oh = blockIdx.y;
  const int i0 = blockIdx.x * 64;
  const int t = threadIdx.x, wave = t >> 6, lane = t & 63;
  const int quad = lane >> 4, ln16 = lane & 15;

  // P-gen mapping: 4 threads per i-row, 16 k each
  const int pr = t >> 2;           // 0..63
  const int ko = (t & 3) * 16;     // 0,16,32,48
  const float si = s[z * NN + i0 + pr];
  const uint32_t* bmrow = bm + (size_t)(z * NN + i0 + pr) * 64;
  const float* db = d + z * NN;

  const char* slabB = (const char*)hS + (size_t)(z * 2 + oh) * 1048576;

  f32x4 acc[4][4];
#pragma unroll
  for (int i = 0; i < 4; ++i)
#pragma unroll
    for (int j = 0; j < 4; ++j) acc[i][j] = (f32x4){0.f, 0.f, 0.f, 0.f};

  const int fslot = ln16 * 4 + (quad ^ ((ln16 >> 1) & 3));
  const int prc = pr & 15, pch = pr >> 4;
  const int ph = ko >> 5, pq0 = (ko >> 3) & 3;  // k-half, first quarter (0 or 2)
  char* pbase = (char*)Plds + ph * 4096 + pch * 1024;
  char* pdst0 = pbase + (prc * 4 + (pq0 ^ ((prc >> 1) & 3))) * 16;
  char* pdst1 = pbase + (prc * 4 + ((pq0 + 1) ^ ((prc >> 1) & 3))) * 16;

  // ---- prologue: prefetch regs for kt=0, then stage tile 0 into buf 0 ----
  uint32_t bw = bmrow[ko >> 5];
  float4 dv[4];
#pragma unroll
  for (int c = 0; c < 4; ++c) dv[c] = *(const float4*)&db[ko + c * 4];
  __builtin_amdgcn_sched_barrier(0);   // pin: dv/bw issue BEFORE stage issue
#pragma unroll
  for (int c = 0; c < 8; ++c) {
    int boff = (c * 4 + wave) * 1024;
    gl2lds16(slabB + boff + lane * 16, (char*)&Blds[0][0] + boff);
  }

  float lsum = 0.f;
  int buf = 0;

  for (int kt = 0; kt < NN; kt += 64) {
    // ---- A: P values for k = kt+ko .. +16 from prefetched regs ----
    // (compiler waits vmcnt(8) here for dv/bw: stage(kt) x8 stays in flight)
    uint32_t bits16 = (bw >> (ko & 16)) & 0xFFFFu;
    u16 pk[16];
#pragma unroll
    for (int cc = 0; cc < 4; ++cc) {
      float4 dq = dv[cc];
#pragma unroll
      for (int e = 0; e < 4; ++e) {
        float dj = (e == 0) ? dq.x : (e == 1) ? dq.y : (e == 2) ? dq.z : dq.w;
        float x = si + dj;
        float xm = fmaxf(x, 0.2f * x);
        float p = ((bits16 >> (cc * 4 + e)) & 1u) ? 0.f : __expf(xm);
        lsum += p;
        pk[cc * 4 + e] = f2bf(p);
      }
    }

    // ---- B: issue next-tile prefetch (regs) then staging (gl2lds) ----
    bool more = (kt + 64 < NN);
    if (more) {
      bw = bmrow[((kt + 64) >> 5) + (ko >> 5)];
#pragma unroll
      for (int c = 0; c < 4; ++c)
        dv[c] = *(const float4*)&db[kt + 64 + ko + c * 4];
      __builtin_amdgcn_sched_barrier(0);  // pin: dv/bw before gl2lds
      const char* gB = slabB + (size_t)(kt + 64) * 512;
      char* bdst = (char*)&Blds[buf ^ 1][0];
#pragma unroll
      for (int c = 0; c < 8; ++c) {
        int boff = (c * 4 + wave) * 1024;
        gl2lds16(gB + boff + lane * 16, bdst + boff);
      }
    }

    // ---- C: write P(kt) to LDS (prev readers finished at barrier G) ----
    *(int4*)pdst0 = *(int4*)&pk[0];
    *(int4*)pdst1 = *(int4*)&pk[8];

    // ---- D/E: counted wait (drain ONLY stage(kt) x8 + my P writes) ----
    if (more)
      asm volatile("s_waitcnt vmcnt(13) lgkmcnt(0)" ::: "memory");
    else
      asm volatile("s_waitcnt vmcnt(0) lgkmcnt(0)" ::: "memory");
    __builtin_amdgcn_s_barrier();
    asm volatile("" ::: "memory");

    // ---- F: fragments + MFMA: 2 k-halves x 4i x 4j ----
    const char* bbase = (const char*)&Blds[buf][0];
#pragma unroll
    for (int h = 0; h < 2; ++h) {
      bf16x8 af[4], bfv[4];
#pragma unroll
      for (int i = 0; i < 4; ++i)
        af[i] = *(const bf16x8*)((const char*)Plds + h * 4096 + i * 1024 + fslot * 16);
#pragma unroll
      for (int j = 0; j < 4; ++j)
        bfv[j] = *(const bf16x8*)(bbase + h * 16384 +
                                  (wave * 4 + j) * 1024 + fslot * 16);
#pragma unroll
      for (int i = 0; i < 4; ++i)
#pragma unroll
        for (int j = 0; j < 4; ++j)
          acc[i][j] = __builtin_amdgcn_mfma_f32_16x16x32_bf16(af[i], bfv[j],
                                                              acc[i][j], 0, 0, 0);
    }

    // ---- G: all waves done reading B[cur]+Plds before next overwrite ----
    asm volatile("" ::: "memory");
    __builtin_amdgcn_s_barrier();
    asm volatile("" ::: "memory");
    buf ^= 1;
  }

  // ---- row sums -> 1/l (block covers full K, sums complete) ----
  lpart[pr * 4 + (t & 3)] = lsum;
  __syncthreads();
  if (t < 64) {
    const float* lp = &lpart[t * 4];
    linv_lds[t] = 1.0f / ((lp[0] + lp[1]) + (lp[2] + lp[3]));
  }
  __syncthreads();

  // ---- epilogue: C/D layout col=lane&15, row=quad*4+reg ----
#pragma unroll
  for (int i = 0; i < 4; ++i) {
#pragma unroll
    for (int r = 0; r < 4; ++r) {
      int m = i * 16 + quad * 4 + r;
      float sc = linv_lds[m];
      float* ob = out + ((size_t)(z * NN) + i0 + m) * NF + oh * 256 + wave * 64;
#pragma unroll
      for (int j = 0; j < 4; ++j) ob[j * 16 + ln16] = acc[i][j][r] * sc;
    }
  }
}

// ---------------------------------------------------------------------------
// launch
// ---------------------------------------------------------------------------
extern "C" void kernel_launch(void* const* d_in, const int* in_sizes, int n_in,
                              void* d_out, int out_size, void* d_ws,
                              size_t ws_size, hipStream_t stream) {
  const float* text  = (const float*)d_in[0];   // [8,2048,512] fp32
  const int*   adj   = (const int*)d_in[1];     // [8,2048,2048] int32
  const float* W     = (const float*)d_in[2];   // [512,512] fp32
  const float* bias  = (const float*)d_in[3];   // [512] fp32
  const float* a_src = (const float*)d_in[4];   // [512] fp32
  const float* a_dst = (const float*)d_in[5];   // [512] fp32
  float* out = (float*)d_out;                   // [8,2048,512] fp32

  // ws layout (bytes), ~37.2 MB
  char* ws = (char*)d_ws;
  u16*      text_bf = (u16*)(ws + 0);            // 16,777,216
  u16*      Wt      = (u16*)(ws + 16777216);     //    524,288
  u16*      hS      = (u16*)(ws + 17301504);     // 16,777,216  slabs
  float*    s       = (float*)(ws + 34078720);   //     65,536
  float*    d       = (float*)(ws + 34144256);   //     65,536
  uint32_t* bmask   = (uint32_t*)(ws + 34209792);// 4,194,304

  // single prep dispatch: conv + W^T + pack + zero(s,d)
  prep_kernel<<<13313, 256, 0, stream>>>(text, W, adj, text_bf, Wt, bmask, s);

  gemm1_kernel<<<dim3(128, 4, 1), 256, 0, stream>>>(Wt, text_bf, bias, a_src,
                                                    a_dst, hS, s, d);

  fused_attn_kernel<<<dim3(NN / 64, 2, NB), 256, 0, stream>>>(bmask, s, d, hS,
                                                              out);
}

// Round 2
// 296.381 us; speedup vs baseline: 1.0111x; 1.0090x over previous
//
#include <hip/hip_runtime.h>
#include <stdint.h>

// Problem constants: B=8, N=2048, F_in=F_out=512
#define NB 8
#define NN 2048
#define NF 512
#define TOTN (NB * NN)   // 16384 nodes total

typedef unsigned short u16;
typedef short bf16x8 __attribute__((ext_vector_type(8)));
typedef float f32x4 __attribute__((ext_vector_type(4)));

__device__ __forceinline__ u16 f2bf(float x) {
  unsigned u = __float_as_uint(x);
  unsigned r = 0x7FFFu + ((u >> 16) & 1u);
  return (u16)((u + r) >> 16);
}

__device__ __forceinline__ void gl2lds16(const void* g, void* l) {
  // async global->LDS, 16B per lane; LDS dst = wave-uniform base + lane*16
  __builtin_amdgcn_global_load_lds((const __attribute__((address_space(1))) void*)g,
                                   (__attribute__((address_space(3))) void*)l,
                                   16, 0, 0);
}

// slab swizzle: within a 16-row chunk, data (row rc, k-quarter q) lives at
// slot = rc*4 + (q ^ ((rc>>1)&3)), 16 B per slot.  (verified conflict-free R3)

// ---------------------------------------------------------------------------
// K1 (prep): text fp32->bf16, W->W^T bf16, zero s/d.
// adj-pack moved OUT (overlapped with gemm1 -- it has no dependency on this).
// ---------------------------------------------------------------------------
__global__ __launch_bounds__(256) void prep_kernel(
    const float* __restrict__ text, const float* __restrict__ W,
    u16* __restrict__ text_bf, u16* __restrict__ Wt,
    float* __restrict__ sd) {
  int blk = blockIdx.x;
  if (blk < 8192) {
    // text conversion: 8192 blocks x 256 thr x float4
    int idx = blk * 256 + threadIdx.x;
    float4 v = ((const float4*)text)[idx];
    ushort4 o;
    o.x = f2bf(v.x); o.y = f2bf(v.y); o.z = f2bf(v.z); o.w = f2bf(v.w);
    ((ushort4*)text_bf)[idx] = o;
  } else if (blk < 9216) {
    // W transpose+convert: 1024 blocks
    int t = (blk - 8192) * 256 + threadIdx.x;
    int o = t >> 9, f = t & 511;
    Wt[o * NF + f] = f2bf(W[f * NF + o]);
  } else {
    // zero s,d (contiguous 131072 B = 8192 float4): 1 block
    float4* p = (float4*)sd;
#pragma unroll
    for (int c = 0; c < 32; ++c)
      p[c * 256 + threadIdx.x] = (float4){0.f, 0.f, 0.f, 0.f};
  }
}

// ---------------------------------------------------------------------------
// K3 (merged): GEMM1 (blocks 0..511) + adj bit-pack (blocks 512..4607).
// Pack is pure HBM streaming (134 MB) with zero dependency on GEMM inputs;
// putting it in the same dispatch lets it co-schedule on CUs alongside the
// compute-bound GEMM (2 GEMM blocks + >=4 pack blocks fit per CU) so the
// region costs max(gemm, pack) instead of gemm + pack.
//
// GEMM1: hidden[o][node] -> pre-swizzled slabs + fused s/d score epilogue.
// hS layout: [z 8][oh 2][kc 64][16KB slab image]; image = 16 chunks(16 o-rows)
// x swizzled slots. Slab (z,oh,kc) holds hidden[o in oh*256..+256][k=kc*32..+32].
// ---------------------------------------------------------------------------
__global__ __launch_bounds__(256) void gemm1_kernel(
    const u16* __restrict__ A,   // Wt [512][512]
    const u16* __restrict__ Bt,  // text_bf [16384][512]
    const float* __restrict__ bias, const float* __restrict__ a_src,
    const float* __restrict__ a_dst, const int* __restrict__ adj,
    u16* __restrict__ hS, float* __restrict__ s, float* __restrict__ d,
    uint32_t* __restrict__ bmout) {
  __shared__ u16 Alds[128 * 32];
  __shared__ u16 Blds[128 * 32];

  const int bid = blockIdx.x;
  const int t = threadIdx.x;

  if (bid >= 512) {
    // ---- adj pack path: 4096 blocks, 32 elems/thread ----
    int gid = (bid - 512) * 256 + t;
    const int4* p = (const int4*)(adj + (size_t)gid * 32);
    uint32_t bits = 0;
#pragma unroll
    for (int c = 0; c < 8; ++c) {
      int4 a = p[c];
      bits |= (uint32_t)(a.x != 0) << (c * 4 + 0);
      bits |= (uint32_t)(a.y != 0) << (c * 4 + 1);
      bits |= (uint32_t)(a.z != 0) << (c * 4 + 2);
      bits |= (uint32_t)(a.w != 0) << (c * 4 + 3);
    }
    bmout[gid] = bits;
    return;
  }

  const int bn = bid & 127, bm_ = bid >> 7;
  const int wave = t >> 6, lane = t & 63;
  const int wm = (wave >> 1) * 64, wn = (wave & 1) * 64;

  f32x4 acc[4][4];
#pragma unroll
  for (int i = 0; i < 4; ++i)
#pragma unroll
    for (int j = 0; j < 4; ++j) acc[i][j] = (f32x4){0.f, 0.f, 0.f, 0.f};

  const int rowA0 = bm_ * 128, rowB0 = bn * 128;
  const int srow = (lane >> 2);
  const int scol = (lane & 3) * 8;

  for (int kt = 0; kt < NF; kt += 32) {
#pragma unroll
    for (int q = 0; q < 2; ++q) {
      int r = wave * 32 + q * 16;
      gl2lds16(A + (size_t)(rowA0 + r + srow) * NF + (kt + scol), &Alds[r * 32]);
    }
#pragma unroll
    for (int q = 0; q < 2; ++q) {
      int r = wave * 32 + q * 16;
      gl2lds16(Bt + (size_t)(rowB0 + r + srow) * NF + (kt + scol), &Blds[r * 32]);
    }
    __syncthreads();

    const int fr = lane & 15;
    const int k0 = (lane >> 4) * 8;
    bf16x8 af[4], bfr[4];
#pragma unroll
    for (int i = 0; i < 4; ++i)
      af[i] = *(const bf16x8*)&Alds[(wm + i * 16 + fr) * 32 + k0];
#pragma unroll
    for (int j = 0; j < 4; ++j)
      bfr[j] = *(const bf16x8*)&Blds[(wn + j * 16 + fr) * 32 + k0];
#pragma unroll
    for (int i = 0; i < 4; ++i)
#pragma unroll
      for (int j = 0; j < 4; ++j)
        acc[i][j] = __builtin_amdgcn_mfma_f32_16x16x32_bf16(af[i], bfr[j],
                                                            acc[i][j], 0, 0, 0);
    __syncthreads();
  }

  const int quad = lane >> 4, ln16 = lane & 15;
  float sa[4] = {0.f, 0.f, 0.f, 0.f}, da[4] = {0.f, 0.f, 0.f, 0.f};
#pragma unroll
  for (int i = 0; i < 4; ++i) {
    int m0 = bm_ * 128 + wm + i * 16 + quad * 4;
#pragma unroll
    for (int r = 0; r < 4; ++r) {
      int m = m0 + r;
      float bv = bias[m];
      float asv = a_src[m], adv = a_dst[m];
      int oh = m >> 8, och = (m >> 4) & 15, rc = m & 15;
#pragma unroll
      for (int j = 0; j < 4; ++j) {
        int n = bn * 128 + wn + j * 16 + ln16;
        float h = acc[i][j][r] + bv;
        int zz = n >> 11, nz = n & 2047;
        int kc = nz >> 5, kin = nz & 31;
        size_t off = ((((size_t)zz * 2 + oh) * 64 + kc) << 13)  // slab, u16 units
                     + (och << 9)
                     + ((size_t)(rc * 4 + ((kin >> 3) ^ ((rc >> 1) & 3))) << 3)
                     + (kin & 7);
        hS[off] = f2bf(h);
        sa[j] = fmaf(h, asv, sa[j]);
        da[j] = fmaf(h, adv, da[j]);
      }
    }
  }
#pragma unroll
  for (int j = 0; j < 4; ++j) {
    float v = sa[j] + __shfl_xor(sa[j], 16, 64);
    v += __shfl_xor(v, 32, 64);
    float w2 = da[j] + __shfl_xor(da[j], 16, 64);
    w2 += __shfl_xor(w2, 32, 64);
    if (quad == 0) {
      int n = bn * 128 + wn + j * 16 + ln16;
      atomicAdd(&s[n], v);
      atomicAdd(&d[n], w2);
    }
  }
}

// ---------------------------------------------------------------------------
// K4 (fused): out[z,i,o] = (1/l_i)*sum_j exp(lrelu(s_i+d_j))·[!adj]·h[j][o]
// 64(i) x 256(o) tile, 4 waves (each 64x64), BK=64, 512 blocks (1-D).
//
// T1 XCD-pinning: z = bid & 7. Workgroups round-robin XCDs by linear id, so
// each XCD's 64 resident blocks all share ONE z -> staging working set
// (hS z-slabs 2 MB + bm 512 KB) fits the 4 MB per-XCD L2; the 512 MB of
// slab staging reads become L2 hits instead of L3 traffic.
//
// PIPELINED (T3+T4): double-buffered B slabs, raw s_barrier, counted waits
// (vmcnt(13) drains only the previous tile's 8 staging ops).
// LDS: 64K (2xB) + 8K (P) + 1.25K = 73.3 KB -> 2 blocks/CU.
// ---------------------------------------------------------------------------
__global__ __launch_bounds__(256, 2) void fused_attn_kernel(
    const uint32_t* __restrict__ bm, const float* __restrict__ s,
    const float* __restrict__ d, const u16* __restrict__ hS,
    float* __restrict__ out) {
  __shared__ u16 Blds[2][16384];   // 2 x 32 KB double buffer
  __shared__ u16 Plds[4096];       // 8 KB = 2 k-half images
  __shared__ float lpart[256];
  __shared__ float linv_lds[64];

  // XCD-aware decode: 8 XCDs, z pinned per XCD (512 blocks % 8 == 0)
  const int bid = blockIdx.x;
  const int z = bid & 7;
  const int oh = (bid >> 3) & 1;
  const int i0 = (bid >> 4) * 64;
  const int t = threadIdx.x, wave = t >> 6, lane = t & 63;
  const int quad = lane >> 4, ln16 = lane & 15;

  // P-gen mapping: 4 threads per i-row, 16 k each
  const int pr = t >> 2;           // 0..63
  const int ko = (t & 3) * 16;     // 0,16,32,48
  const float si = s[z * NN + i0 + pr];
  const uint32_t* bmrow = bm + (size_t)(z * NN + i0 + pr) * 64;
  const float* db = d + z * NN;

  const char* slabB = (const char*)hS + (size_t)(z * 2 + oh) * 1048576;

  f32x4 acc[4][4];
#pragma unroll
  for (int i = 0; i < 4; ++i)
#pragma unroll
    for (int j = 0; j < 4; ++j) acc[i][j] = (f32x4){0.f, 0.f, 0.f, 0.f};

  const int fslot = ln16 * 4 + (quad ^ ((ln16 >> 1) & 3));
  const int prc = pr & 15, pch = pr >> 4;
  const int ph = ko >> 5, pq0 = (ko >> 3) & 3;  // k-half, first quarter (0 or 2)
  char* pbase = (char*)Plds + ph * 4096 + pch * 1024;
  char* pdst0 = pbase + (prc * 4 + (pq0 ^ ((prc >> 1) & 3))) * 16;
  char* pdst1 = pbase + (prc * 4 + ((pq0 + 1) ^ ((prc >> 1) & 3))) * 16;

  // ---- prologue: prefetch regs for kt=0, then stage tile 0 into buf 0 ----
  uint32_t bw = bmrow[ko >> 5];
  float4 dv[4];
#pragma unroll
  for (int c = 0; c < 4; ++c) dv[c] = *(const float4*)&db[ko + c * 4];
  __builtin_amdgcn_sched_barrier(0);   // pin: dv/bw issue BEFORE stage issue
#pragma unroll
  for (int c = 0; c < 8; ++c) {
    int boff = (c * 4 + wave) * 1024;
    gl2lds16(slabB + boff + lane * 16, (char*)&Blds[0][0] + boff);
  }

  float lsum = 0.f;
  int buf = 0;

  for (int kt = 0; kt < NN; kt += 64) {
    // ---- A: P values for k = kt+ko .. +16 from prefetched regs ----
    // (compiler waits vmcnt(8) here for dv/bw: stage(kt) x8 stays in flight)
    uint32_t bits16 = (bw >> (ko & 16)) & 0xFFFFu;
    u16 pk[16];
#pragma unroll
    for (int cc = 0; cc < 4; ++cc) {
      float4 dq = dv[cc];
#pragma unroll
      for (int e = 0; e < 4; ++e) {
        float dj = (e == 0) ? dq.x : (e == 1) ? dq.y : (e == 2) ? dq.z : dq.w;
        float x = si + dj;
        float xm = fmaxf(x, 0.2f * x);
        float p = ((bits16 >> (cc * 4 + e)) & 1u) ? 0.f : __expf(xm);
        lsum += p;
        pk[cc * 4 + e] = f2bf(p);
      }
    }

    // ---- B: issue next-tile prefetch (regs) then staging (gl2lds) ----
    bool more = (kt + 64 < NN);
    if (more) {
      bw = bmrow[((kt + 64) >> 5) + (ko >> 5)];
#pragma unroll
      for (int c = 0; c < 4; ++c)
        dv[c] = *(const float4*)&db[kt + 64 + ko + c * 4];
      __builtin_amdgcn_sched_barrier(0);  // pin: dv/bw before gl2lds
      const char* gB = slabB + (size_t)(kt + 64) * 512;
      char* bdst = (char*)&Blds[buf ^ 1][0];
#pragma unroll
      for (int c = 0; c < 8; ++c) {
        int boff = (c * 4 + wave) * 1024;
        gl2lds16(gB + boff + lane * 16, bdst + boff);
      }
    }

    // ---- C: write P(kt) to LDS (prev readers finished at barrier G) ----
    *(int4*)pdst0 = *(int4*)&pk[0];
    *(int4*)pdst1 = *(int4*)&pk[8];

    // ---- D/E: counted wait (drain ONLY stage(kt) x8 + my P writes) ----
    if (more)
      asm volatile("s_waitcnt vmcnt(13) lgkmcnt(0)" ::: "memory");
    else
      asm volatile("s_waitcnt vmcnt(0) lgkmcnt(0)" ::: "memory");
    __builtin_amdgcn_s_barrier();
    asm volatile("" ::: "memory");

    // ---- F: fragments + MFMA: 2 k-halves x 4i x 4j ----
    const char* bbase = (const char*)&Blds[buf][0];
#pragma unroll
    for (int h = 0; h < 2; ++h) {
      bf16x8 af[4], bfv[4];
#pragma unroll
      for (int i = 0; i < 4; ++i)
        af[i] = *(const bf16x8*)((const char*)Plds + h * 4096 + i * 1024 + fslot * 16);
#pragma unroll
      for (int j = 0; j < 4; ++j)
        bfv[j] = *(const bf16x8*)(bbase + h * 16384 +
                                  (wave * 4 + j) * 1024 + fslot * 16);
#pragma unroll
      for (int i = 0; i < 4; ++i)
#pragma unroll
        for (int j = 0; j < 4; ++j)
          acc[i][j] = __builtin_amdgcn_mfma_f32_16x16x32_bf16(af[i], bfv[j],
                                                              acc[i][j], 0, 0, 0);
    }

    // ---- G: all waves done reading B[cur]+Plds before next overwrite ----
    asm volatile("" ::: "memory");
    __builtin_amdgcn_s_barrier();
    asm volatile("" ::: "memory");
    buf ^= 1;
  }

  // ---- row sums -> 1/l (block covers full K, sums complete) ----
  lpart[pr * 4 + (t & 3)] = lsum;
  __syncthreads();
  if (t < 64) {
    const float* lp = &lpart[t * 4];
    linv_lds[t] = 1.0f / ((lp[0] + lp[1]) + (lp[2] + lp[3]));
  }
  __syncthreads();

  // ---- epilogue: C/D layout col=lane&15, row=quad*4+reg ----
#pragma unroll
  for (int i = 0; i < 4; ++i) {
#pragma unroll
    for (int r = 0; r < 4; ++r) {
      int m = i * 16 + quad * 4 + r;
      float sc = linv_lds[m];
      float* ob = out + ((size_t)(z * NN) + i0 + m) * NF + oh * 256 + wave * 64;
#pragma unroll
      for (int j = 0; j < 4; ++j) ob[j * 16 + ln16] = acc[i][j][r] * sc;
    }
  }
}

// ---------------------------------------------------------------------------
// launch
// ---------------------------------------------------------------------------
extern "C" void kernel_launch(void* const* d_in, const int* in_sizes, int n_in,
                              void* d_out, int out_size, void* d_ws,
                              size_t ws_size, hipStream_t stream) {
  const float* text  = (const float*)d_in[0];   // [8,2048,512] fp32
  const int*   adj   = (const int*)d_in[1];     // [8,2048,2048] int32
  const float* W     = (const float*)d_in[2];   // [512,512] fp32
  const float* bias  = (const float*)d_in[3];   // [512] fp32
  const float* a_src = (const float*)d_in[4];   // [512] fp32
  const float* a_dst = (const float*)d_in[5];   // [512] fp32
  float* out = (float*)d_out;                   // [8,2048,512] fp32

  // ws layout (bytes), ~37.2 MB
  char* ws = (char*)d_ws;
  u16*      text_bf = (u16*)(ws + 0);            // 16,777,216
  u16*      Wt      = (u16*)(ws + 16777216);     //    524,288
  u16*      hS      = (u16*)(ws + 17301504);     // 16,777,216  slabs
  float*    s       = (float*)(ws + 34078720);   //     65,536
  float*    d       = (float*)(ws + 34144256);   //     65,536
  uint32_t* bmask   = (uint32_t*)(ws + 34209792);// 4,194,304

  // prep: conv + W^T + zero(s,d)   (adj-pack moved into gemm1's dispatch)
  prep_kernel<<<9217, 256, 0, stream>>>(text, W, text_bf, Wt, s);

  // GEMM1 (512 blocks) + adj-pack (4096 blocks) overlapped in one dispatch
  gemm1_kernel<<<4608, 256, 0, stream>>>(Wt, text_bf, bias, a_src, a_dst, adj,
                                         hS, s, d, bmask);

  fused_attn_kernel<<<512, 256, 0, stream>>>(bmask, s, d, hS, out);
}